// Round 3
// baseline (125.786 us; speedup 1.0000x reference)
//
#include <hip/hip_runtime.h>
#include <hip/hip_bf16.h>
#include <math.h>

// Problem constants: B=64, L=256, H=64
#define PB 64
#define PL 256
#define PH 64
#define TEMP 0.07f
#define NEG_INF_F (-1e9f)

#define KSTRIDE 72   // bf16 elements per staged K row (64 + 8 pad; 144 B, 16B-aligned)

typedef short short8 __attribute__((ext_vector_type(8)));   // 8 bf16 bit-patterns
typedef float f32x4 __attribute__((ext_vector_type(4)));

// fp32 pair -> packed bf16x2 (RTNE; lowers to v_cvt_pk_bf16_f32 on gfx950)
__device__ __forceinline__ unsigned int pkbf(float a, float b) {
    __hip_bfloat162 h = __float22bfloat162_rn(float2{a, b});
    union { __hip_bfloat162 h2; unsigned int u; } cvt;
    cvt.h2 = h;
    return cvt.u;
}

// ---------------- main scores kernel: one block per (b,c) ----------------
__global__ __launch_bounds__(256, 4)
void colbert_scores_mfma(const float* __restrict__ Qg,
                         const float* __restrict__ Kg,
                         const int*   __restrict__ qmask,
                         const int*   __restrict__ kmask,
                         float*       __restrict__ scores) {
    const int c = blockIdx.x;
    const int b = blockIdx.y;
    const int tid  = threadIdx.x;
    const int wave = tid >> 6;
    const int lane = tid & 63;
    const int n    = lane & 15;        // col / row-within-tile index
    const int g    = (lane >> 4) & 3;  // quad index

    __shared__ __align__(16) unsigned short Ks[PL * KSTRIDE];  // 36 KB bf16
    __shared__ float bmF[PL];   // key-mask bias: 0 or -1e9
    __shared__ float qmF[PL];
    __shared__ float red[4];

    // Stage masks
    bmF[tid] = kmask[c * PL + tid] ? 0.0f : NEG_INF_F;
    qmF[tid] = (float)qmask[b * PL + tid];

    // Stage K_c (256 x 64 fp32) into LDS as bf16, padded stride.
    {
        const float* Kbase = Kg + ((size_t)c * PL) * PH;
        #pragma unroll
        for (int it = 0; it < (PL * PH) / (256 * 4); ++it) {   // 16 iters
            int lin = it * 256 + tid;          // float4 index, 4096 total
            int row = lin >> 4;                // 16 float4 per 64-col row
            int c4  = lin & 15;
            float4 v = *(const float4*)(Kbase + (size_t)lin * 4);
            uint2 o;
            o.x = pkbf(v.x, v.y);
            o.y = pkbf(v.z, v.w);
            *(uint2*)(&Ks[row * KSTRIDE + c4 * 4]) = o;
        }
    }

    // Load this wave's A-fragments (Q) from global fp32, convert to bf16.
    // Wave handles q rows [wave*64, wave*64+64). A-frag (16x16x32):
    // lane holds A[m=lane&15][k=g*8+j], j=0..7.
    const int qw0 = wave * 64;
    short8 afrag[4][2];
    {
        const float* Qrow = Qg + ((size_t)b * PL) * PH;
        #pragma unroll
        for (int rt = 0; rt < 4; ++rt) {
            const float* p = Qrow + (size_t)(qw0 + rt * 16 + n) * PH + g * 8;
            float4 f0 = *(const float4*)(p);
            float4 f1 = *(const float4*)(p + 4);
            float4 f2 = *(const float4*)(p + 32);
            float4 f3 = *(const float4*)(p + 36);
            union { short8 s8; unsigned int u[4]; } a0, a1;
            a0.u[0] = pkbf(f0.x, f0.y); a0.u[1] = pkbf(f0.z, f0.w);
            a0.u[2] = pkbf(f1.x, f1.y); a0.u[3] = pkbf(f1.z, f1.w);
            a1.u[0] = pkbf(f2.x, f2.y); a1.u[1] = pkbf(f2.z, f2.w);
            a1.u[2] = pkbf(f3.x, f3.y); a1.u[3] = pkbf(f3.z, f3.w);
            afrag[rt][0] = a0.s8;
            afrag[rt][1] = a1.s8;
        }
    }

    __syncthreads();   // Ks + masks visible

    // Preload this lane's per-col-tile mask bias (16 values, kept in VGPRs).
    float biasv[16];
    #pragma unroll
    for (int ct = 0; ct < 16; ++ct) biasv[ct] = bmF[ct * 16 + n];

    // Running per-row masked max: maxv[rt][r] for row qw0 + rt*16 + g*4 + r
    float maxv[4][4];
    #pragma unroll
    for (int rt = 0; rt < 4; ++rt)
        #pragma unroll
        for (int r = 0; r < 4; ++r) maxv[rt][r] = NEG_INF_F;

    // 16 col-tiles of 16 k-tokens. LDS reads use immediate offsets off krow0.
    const unsigned short* krow0 = &Ks[n * KSTRIDE + g * 8];
    #pragma unroll
    for (int ct = 0; ct < 16; ++ct) {
        short8 b0 = *(const short8*)(krow0 + ct * 16 * KSTRIDE);
        short8 b1 = *(const short8*)(krow0 + ct * 16 * KSTRIDE + 32);
        const float bias = biasv[ct];
        const f32x4 bias4 = {bias, bias, bias, bias};

        f32x4 acc[4];
        #pragma unroll
        for (int rt = 0; rt < 4; ++rt)
            acc[rt] = __builtin_amdgcn_mfma_f32_16x16x32_bf16(afrag[rt][0], b0, bias4, 0, 0, 0);
        #pragma unroll
        for (int rt = 0; rt < 4; ++rt)
            acc[rt] = __builtin_amdgcn_mfma_f32_16x16x32_bf16(afrag[rt][1], b1, acc[rt], 0, 0, 0);

        // running max (mask already folded in via bias; C layout: col=n, row=g*4+r)
        #pragma unroll
        for (int rt = 0; rt < 4; ++rt)
            #pragma unroll
            for (int r = 0; r < 4; ++r)
                maxv[rt][r] = fmaxf(maxv[rt][r], acc[rt][r]);
    }

    // Max across the 16 lanes (cols) of each quad group.
    #pragma unroll
    for (int rt = 0; rt < 4; ++rt)
        #pragma unroll
        for (int r = 0; r < 4; ++r) {
            float mv = maxv[rt][r];
            mv = fmaxf(mv, __shfl_xor(mv, 1, 16));
            mv = fmaxf(mv, __shfl_xor(mv, 2, 16));
            mv = fmaxf(mv, __shfl_xor(mv, 4, 16));
            mv = fmaxf(mv, __shfl_xor(mv, 8, 16));
            maxv[rt][r] = mv;
        }

    // qmask-weighted sum; count each row once (n==0 lanes).
    float partial = 0.0f;
    if (n == 0) {
        #pragma unroll
        for (int rt = 0; rt < 4; ++rt)
            #pragma unroll
            for (int r = 0; r < 4; ++r) {
                int row = qw0 + rt * 16 + g * 4 + r;
                partial += maxv[rt][r] * qmF[row];
            }
    }
    partial += __shfl_xor(partial, 16, 64);
    partial += __shfl_xor(partial, 32, 64);
    if (lane == 0) red[wave] = partial;
    __syncthreads();
    if (tid == 0) {
        float total = red[0] + red[1] + red[2] + red[3];
        scores[b * PB + c] = total * (1.0f / TEMP);
    }
}

// ---------------- finalize: log-softmax CE ----------------
__global__ void finalize_kernel(const float* __restrict__ scores,
                                const int*   __restrict__ labels,
                                float*       __restrict__ out) {
    const int r = threadIdx.x;   // 64 threads, one per row
    const float* row = scores + r * PB;
    float mx = NEG_INF_F;
    for (int j = 0; j < PB; ++j) mx = fmaxf(mx, row[j]);
    float se = 0.0f;
    for (int j = 0; j < PB; ++j) se += expf(row[j] - mx);
    float logp_diag = row[r] - mx - logf(se);
    float w = (float)labels[r];
    float wd = w * logp_diag;
    #pragma unroll
    for (int off = 32; off >= 1; off >>= 1) {
        wd += __shfl_xor(wd, off, 64);
        w  += __shfl_xor(w,  off, 64);
    }
    if (r == 0) out[0] = -wd / fmaxf(w, 1.0f);
}

extern "C" void kernel_launch(void* const* d_in, const int* in_sizes, int n_in,
                              void* d_out, int out_size, void* d_ws, size_t ws_size,
                              hipStream_t stream) {
    const float* Q      = (const float*)d_in[0];
    const float* K      = (const float*)d_in[1];
    const int*   labels = (const int*)d_in[2];
    const int*   qmask  = (const int*)d_in[3];
    const int*   kmask  = (const int*)d_in[4];
    float*       out    = (float*)d_out;
    float*       scores = (float*)d_ws;   // 64*64 fp32

    dim3 grid(PB, PB);   // x = c (key batch), y = b (query batch)
    colbert_scores_mfma<<<grid, 256, 0, stream>>>(Q, K, qmask, kmask, scores);
    finalize_kernel<<<1, 64, 0, stream>>>(scores, labels, out);
}